// Round 18
// baseline (198.296 us; speedup 1.0000x reference)
//
#include <hip/hip_runtime.h>

#define HH 16
#define SS 2048
#define DD 128

// output offsets (f32 elements) in d_out
#define O0 0u          // attn_output  [1,16,2048,128]
#define O1 4194304u    // k_quant      [1,16,2048,128]
#define O2 8388608u    // k_scale      [1,16,1,128]
#define O3 8390656u    // k_sp_val     [24576]
#define O4 8415232u    // k_sp_idx     [24576]
#define O5 8439808u    // v_quant      [1,16,2048,128]
#define O6 12634112u   // v_scale      [1,16,2048,1]
#define O7 12666880u   // v_sp_val     [139264]
#define O8 12806144u   // v_sp_idx     [139264]

using bf16x8 = __attribute__((ext_vector_type(8))) short;
using f32x4  = __attribute__((ext_vector_type(4))) float;

static __device__ __forceinline__ unsigned short f2bf(float f) {
  union { float f; unsigned u; } x; x.f = f;
  unsigned r = x.u + 0x7fffu + ((x.u >> 16) & 1u);   // RNE
  return (unsigned short)(r >> 16);
}

// HW packed f32->bf16 (RNE): lo -> [15:0], hi -> [31:16]
static __device__ __forceinline__ unsigned pk2bf(float lo, float hi) {
  unsigned r;
  asm("v_cvt_pk_bf16_f32 %0, %1, %2" : "=v"(r) : "v"(lo), "v"(hi));
  return r;
}

typedef __attribute__((address_space(1))) const unsigned int gu32_t;
typedef __attribute__((address_space(3))) unsigned int lu32_t;
static __device__ __forceinline__ void gl_lds16(const void* g, void* l) {
  __builtin_amdgcn_global_load_lds((gu32_t*)g, (lu32_t*)l, 16, 0, 0);
}

#define INS9(a_, v_, i_)                                              \
  if ((a_) > aab[8]) {                                                \
    aab[8] = (a_); av[8] = (v_); ai[8] = (i_);                        \
    _Pragma("unroll")                                                 \
    for (int jj = 8; jj > 0; --jj) {                                  \
      if (aab[jj] > aab[jj - 1]) {                                    \
        float ta = aab[jj]; aab[jj] = aab[jj - 1]; aab[jj - 1] = ta;  \
        float tv = av[jj];  av[jj]  = av[jj - 1];  av[jj - 1]  = tv;  \
        int   ti = ai[jj];  ai[jj]  = ai[jj - 1];  ai[jj - 1]  = ti;  \
      }                                                               \
    }                                                                 \
  }

// ---------------------------------------------------------------- prep (flat 3840 blocks, 9.2 KB LDS):
//  x < 512  : K fragments (1 tile each, coalesced loads + cvt_pk, no LDS)
//  x < 1536 : V transposed fragments — HALF-tiles (64 tok x 64 ch), transpose-at-write
//  x < 1792 : K partial top-9 scan (aliases the 9216 B scratch)
//  x >= 1792: V quant (one wave per token, register-only)
__global__ __launch_bounds__(256) void prep_kv(const float* __restrict__ K,
                                               const float* __restrict__ V,
                                               uint4* __restrict__ WK,
                                               uint4* __restrict__ WV,
                                               float* __restrict__ wval,
                                               int* __restrict__ widx,
                                               float* __restrict__ out) {
  __shared__ unsigned short T2u[64 * 72];   // 9216 B
  const int bid = blockIdx.x;
  const int tid = threadIdx.x;

  if (bid < 512) {
    // ---- K fragments for kvt = bid&31 : coalesced source, permuted dest
    const int h   = bid >> 5;
    const int kvt = bid & 31;
    const float* Kh = K + ((size_t)h * SS + (size_t)kvt * 64) * DD;
    #pragma unroll
    for (int it = 0; it < 4; ++it) {
      const int idx = it * 256 + tid;          // 0..1023
      const int row = idx >> 4;                // 0..63
      const int c8  = idx & 15;                // 0..15
      const float* src = Kh + (size_t)row * DD + c8 * 8;
      const float4 a = *(const float4*)src;
      const float4 b = *(const float4*)(src + 4);
      uint4 r;
      r.x = pk2bf(a.x, a.y);
      r.y = pk2bf(a.z, a.w);
      r.z = pk2bf(b.x, b.y);
      r.w = pk2bf(b.z, b.w);
      const int slot = ((row >> 4) * 4 + (c8 >> 2)) * 64 + (c8 & 3) * 16 + (row & 15);
      WK[(size_t)(h * 32 + kvt) * 1024 + slot] = r;
    }

  } else if (bid < 1536) {
    // ---- V half-tile: tile ht = (bid-512)>>1, channels [half*64, half*64+64)
    const int vb   = bid - 512;
    const int ht   = vb >> 1;
    const int half = vb & 1;
    const int n0   = half * 64;
    const float* Vh = V + (size_t)(ht >> 5) * (SS * DD) + (size_t)(ht & 31) * 64 * DD;

    // stage transposed bf16: T2u[n-n0][k^swz(n)] = bf16(V[k][n]); 2 row-pair items/thread
    #pragma unroll
    for (int it = 0; it < 2; ++it) {
      const int p    = it * 256 + tid;     // 0..511 : 32 row-pairs x 16 col-quads
      const int row  = (p >> 4) * 2;       // even row (k)
      const int col  = n0 + (p & 15) * 4;  // global channel
      const float4 a = *(const float4*)(Vh + (size_t)row * DD + col);
      const float4 b = *(const float4*)(Vh + (size_t)(row + 1) * DD + col);
      const float avv[4] = {a.x, a.y, a.z, a.w};
      const float bvv[4] = {b.x, b.y, b.z, b.w};
      #pragma unroll
      for (int jj = 0; jj < 4; ++jj) {
        const int n   = col + jj;
        const int swz = ((n >> 3) & 7) << 3;
        const int kk  = row ^ swz;         // even; kk+1 == (row+1)^swz
        *(unsigned*)&T2u[(n - n0) * 72 + kk] = pk2bf(avv[jj], bvv[jj]);
      }
    }
    __syncthreads();

    // this half's 8 chunks: c in [half*4, half*4+4), tk in {0,1} — one b128 per slot
    uint4* dst = WV + (size_t)ht * 1024;
    #pragma unroll
    for (int it = 0; it < 2; ++it) {
      const int s2   = it * 256 + tid;     // 0..511
      const int ch8  = s2 >> 6;            // 0..7 local chunk
      const int l    = s2 & 63;
      const int c    = half * 4 + (ch8 >> 1);
      const int tk   = ch8 & 1;
      const int chunk = c * 2 + tk;
      const int n    = c * 16 + (l & 15);
      const int k0   = tk * 32 + (l >> 4) * 8;
      const int swz  = ((n >> 3) & 7) << 3;
      dst[chunk * 64 + l] = *(const uint4*)&T2u[(n - n0) * 72 + (k0 ^ swz)];
    }

  } else if (bid < 1792) {
    // ---- K scan: partial top-9 over 128-token stripe (h, sb)
    const int xb = bid - 1536;
    const int h  = xb >> 4;
    const int sb = xb & 15;
    const float* Kh = K + (size_t)h * (SS * DD);
    const int d   = tid & 127;
    const int sub = tid >> 7;
    const int s0  = sb * 128 + sub * 64;

    float aab[9], av[9]; int ai[9];
    #pragma unroll
    for (int j = 0; j < 9; ++j) { aab[j] = -1.f; av[j] = 0.f; ai[j] = 0; }
    for (int ib = 0; ib < 64; ib += 8) {
      float vv[8];
      #pragma unroll
      for (int u = 0; u < 8; ++u)
        vv[u] = Kh[((size_t)(s0 + ib + u) << 7) + d];
      #pragma unroll
      for (int u = 0; u < 8; ++u) {
        const int s = s0 + ib + u;
        const float v = (s < 4) ? 0.f : vv[u];          // sink zeroing (k_iso)
        const float a = fabsf(v);
        INS9(a, v, s)
      }
    }
    float* lvf = (float*)T2u;               // 1152 floats + 1152 ints = 9216 B exactly
    int*   lii = (int*)T2u + 1152;
    if (sub == 1) {
      #pragma unroll
      for (int j = 0; j < 9; ++j) { lvf[d * 9 + j] = av[j]; lii[d * 9 + j] = ai[j]; }
    }
    __syncthreads();
    if (sub == 0) {
      #pragma unroll
      for (int j = 0; j < 9; ++j) {                     // merge sub1 (higher tokens)
        const float v = lvf[d * 9 + j];
        const int  s2 = lii[d * 9 + j];
        const float a = fabsf(v);
        INS9(a, v, s2)
      }
      const int base = (sb * 2048 + h * 128 + d) * 9;   // [sb][2048 ch][9] coalesced
      #pragma unroll
      for (int j = 0; j < 9; ++j) { wval[base + j] = av[j]; widx[base + j] = ai[j]; }
    }

  } else {
    // ---- V quant: one wave per token, register-only butterfly top-5
    const int gw = ((bid - 1792) << 2) + (tid >> 6);  // token id h*S+s
    const int l  = tid & 63;
    const int s  = gw & (SS - 1);
    const float2 v2 = ((const float2*)(V + (size_t)gw * DD))[l];
    const bool sink = (s < 4);
    const float w0 = sink ? 0.f : v2.x;
    const float w1 = sink ? 0.f : v2.y;
    float a0 = fabsf(w0), a1 = fabsf(w1);
    const int d0 = 2 * l, d1 = 2 * l + 1;

    float oval[4]; int oidx[4]; float scale = 0.f;
    #pragma unroll
    for (int rnd = 0; rnd < 5; ++rnd) {
      float ba; int bd; float bv;
      if (a1 > a0) { ba = a1; bd = d1; bv = w1; }
      else         { ba = a0; bd = d0; bv = w0; }
      #pragma unroll
      for (int m = 1; m < 64; m <<= 1) {
        const float oa = __shfl_xor(ba, m);
        const int   od = __shfl_xor(bd, m);
        const float ov = __shfl_xor(bv, m);
        if (oa > ba || (oa == ba && od < bd)) { ba = oa; bd = od; bv = ov; }
      }
      if (rnd < 4) {
        oval[rnd] = bv; oidx[rnd] = bd;
        if (bd == d0) a0 = -1.f;
        if (bd == d1) a1 = -1.f;
      } else {
        scale = fmaxf(ba, 1e-8f) / 7.0f;   // 5th largest = absmax of dense remainder
      }
    }

    const bool z0 = (oidx[0] == d0) | (oidx[1] == d0) | (oidx[2] == d0) | (oidx[3] == d0);
    const bool z1 = (oidx[0] == d1) | (oidx[1] == d1) | (oidx[2] == d1) | (oidx[3] == d1);
    const float q0 = z0 ? 0.f : fminf(7.f, fmaxf(-7.f, rintf(w0 / scale)));
    const float q1 = z1 ? 0.f : fminf(7.f, fmaxf(-7.f, rintf(w1 / scale)));
    float2 pack; pack.x = q0; pack.y = q1;
    *(float2*)(out + O5 + (size_t)gw * DD + d0) = pack;

    if (l == 0) {
      out[O6 + gw] = scale;
      #pragma unroll
      for (int j = 0; j < 4; ++j) {
        out[O7 + gw * 4 + j] = oval[j];
        out[O8 + gw * 4 + j] = (float)(gw * DD + oidx[j]);   // exact (< 2^23)
      }
    }
  }
}

// ---------------------------------------------------------------- attention dispatch:
//  bid < 8   : K merge + sink appends (FIRST — overlaps attn)
//  bid >= 8  : attention — 128-k per barrier (2 subtiles), deferred row-sum reduce
__global__ __launch_bounds__(256) void attn_ws(const float* __restrict__ Q,
                                               const uint4* __restrict__ WK,
                                               const uint4* __restrict__ WV,
                                               const float* __restrict__ wval,
                                               const int* __restrict__ widx,
                                               const float* __restrict__ K,
                                               const float* __restrict__ V,
                                               float* __restrict__ O) {
  const int bid = blockIdx.x;
  const int tid = threadIdx.x;

  if (bid < 8) {
    // ---- K merge: coalesced partials + reg double-buffer (8 blocks x 256)
    const int ch = bid * 256 + tid;                // 2048 channels
    const int h = ch >> 7, d = ch & 127;

    float aab[9], av[9]; int ai[9];
    #pragma unroll
    for (int j = 0; j < 9; ++j) { aab[j] = -1.f; av[j] = 0.f; ai[j] = 0; }

    float va[9], vb[9]; int ia[9], ib[9];
    {
      const int b0 = ch * 9;                       // sb = 0
      #pragma unroll
      for (int j = 0; j < 9; ++j) { va[j] = wval[b0 + j]; ia[j] = widx[b0 + j]; }
    }
    for (int sb = 0; sb < 16; ++sb) {              // token order -> stable ties
      if (sb < 15) {
        const int nb = ((sb + 1) * 2048 + ch) * 9; // prefetch next stripe
        #pragma unroll
        for (int j = 0; j < 9; ++j) { vb[j] = wval[nb + j]; ib[j] = widx[nb + j]; }
      }
      #pragma unroll
      for (int j = 0; j < 9; ++j) {
        const float v = va[j];
        const int  si = ia[j];
        const float a = fabsf(v);
        INS9(a, v, si)
      }
      #pragma unroll
      for (int j = 0; j < 9; ++j) { va[j] = vb[j]; ia[j] = ib[j]; }
    }

    const float scale = fmaxf(aab[8], 1e-8f) / 7.0f;
    O[O2 + ch] = scale;
    #pragma unroll
    for (int j = 0; j < 8; ++j) {
      O[O3 + ch * 8u + j] = av[j];
      O[O4 + ch * 8u + j] = (float)((h * SS + ai[j]) * DD + d);
    }
    #pragma unroll
    for (int u = 0; u < 4; ++u) {
      const int i  = ch * 4 + u;
      const int hh = i >> 9;
      const int r  = i & 511;
      const int flat = hh * (SS * DD) + r;
      const float fidx = (float)flat;
      O[O3 + 16384u + i]  = K[flat];
      O[O4 + 16384u + i]  = fidx;
      O[O7 + 131072u + i] = V[flat];
      O[O8 + 131072u + i] = fidx;
    }
    return;
  }

  const int abid = bid - 8;
  const int x  = abid & 7;          // XCD
  const int kk = abid >> 3;
  const int p_ = kk >> 5;
  const int r  = kk & 31;
  const int h  = x * 2 + (r & 1);
  const int jj = r >> 1;
  const int qb = p_ ? (31 - jj) : jj;  // CU-pair balance: qb with 31-qb
  const int q0 = qb << 6;
  const int w   = tid >> 6;
  const int l   = tid & 63;
  const int l15 = l & 15;
  const int lg  = l >> 4;

  __shared__ uint4 Kt[2][2048];            // 2 x 32 KB (pair of 64-k subtiles per buffer)
  __shared__ unsigned short Pl[4][16][72]; // per-wave P buffer (row = q-local)

  bf16x8 qf[4];
  {
    const float* qp = Q + (size_t)h * (SS * DD) + (size_t)(q0 + w * 16 + l15) * DD + lg * 8;
    #pragma unroll
    for (int t = 0; t < 4; ++t) {
      const float4 a = *(const float4*)(qp + t * 32);
      const float4 b = *(const float4*)(qp + t * 32 + 4);
      bf16x8 f;
      f[0] = (short)f2bf(a.x); f[1] = (short)f2bf(a.y);
      f[2] = (short)f2bf(a.z); f[3] = (short)f2bf(a.w);
      f[4] = (short)f2bf(b.x); f[5] = (short)f2bf(b.y);
      f[6] = (short)f2bf(b.z); f[7] = (short)f2bf(b.w);
      qf[t] = f;
    }
  }

  f32x4 acc[8];
  #pragma unroll
  for (int c = 0; c < 8; ++c) acc[c] = (f32x4){0.f, 0.f, 0.f, 0.f};
  float lrow = 0.f;                  // per-lane partial denom; reduced ONCE in epilogue

  const float sc2 = 0.08838834764831845f * 1.4426950408889634f;  // /sqrt(128)*log2(e)

  // prologue: stage tiles 0,1 into buffer 0 — 8 chunks per wave
  {
    const size_t tbase = (size_t)(h * 32) * 1024;
    #pragma unroll
    for (int i = 0; i < 8; ++i) {
      const int ch = (w << 3) + i;             // 0..31
      gl_lds16(WK + tbase + ch * 64 + l, &Kt[0][ch * 64]);
    }
  }
  __syncthreads();

  const int npair = (qb >> 1) + 1;
  for (int it = 0; it < npair; ++it) {
    const int cur = it & 1;
    const int kt0 = it * 2;
    const bool has1 = (kt0 + 1 <= qb);

    // V frags for kt0 -> regs (coalesced; latency hides under QK0)
    uint4 vbr[16];
    {
      const uint4* gv = WV + (size_t)(h * 32 + kt0) * 1024 + l;
      #pragma unroll
      for (int c8 = 0; c8 < 16; ++c8) vbr[c8] = gv[c8 * 64];
    }

    // issue next pair's K staging
    if (it + 1 < npair) {
      const size_t tbase = (size_t)(h * 32 + kt0 + 2) * 1024;
      #pragma unroll
      for (int i = 0; i < 8; ++i) {
        const int ch = (w << 3) + i;
        gl_lds16(WK + tbase + ch * 64 + l, &Kt[cur ^ 1][ch * 64]);
      }
    }

    // ======== subtile 0
    {
      const bool diag = (kt0 == qb);
      const int ctmax = diag ? (w + 1) : 4;
      float p[4][4];
      __builtin_amdgcn_s_setprio(1);
      #pragma unroll
      for (int ct = 0; ct < 4; ++ct) {
        if (ct < ctmax) {
          f32x4 a = (f32x4){0.f, 0.f, 0.f, 0.f};
          #pragma unroll
          for (int t = 0; t < 4; ++t) {
            bf16x8 kb = ((const bf16x8*)Kt[cur])[(ct * 4 + t) * 64 + l];
            a = __builtin_amdgcn_mfma_f32_16x16x32_bf16(kb, qf[t], a, 0, 0, 0);
          }
          #pragma unroll
          for (int r2 = 0; r2 < 4; ++r2) {
            float s = a[r2] * sc2;
            if (diag) {
              const int koff = ct * 16 + lg * 4 + r2;
              s = (koff > w * 16 + l15) ? -1e30f : s;
            }
            p[ct][r2] = s;
          }
        }
      }
      __builtin_amdgcn_s_setprio(0);

      #pragma unroll
      for (int ct = 0; ct < 4; ++ct) {
        if (ct < ctmax) {
          #pragma unroll
          for (int r2 = 0; r2 < 4; ++r2) {
            const float e = exp2f(p[ct][r2]);
            p[ct][r2] = e;
            lrow += e;
          }
        } else {
          #pragma unroll
          for (int r2 = 0; r2 < 4; ++r2) p[ct][r2] = 0.f;
        }
      }

      #pragma unroll
      for (int ct = 0; ct < 4; ++ct) {
        uint2 pk;
        pk.x = (unsigned)f2bf(p[ct][0]) | ((unsigned)f2bf(p[ct][1]) << 16);
        pk.y = (unsigned)f2bf(p[ct][2]) | ((unsigned)f2bf(p[ct][3]) << 16);
        *(uint2*)&Pl[w][l15][ct * 16 + lg * 4] = pk;
      }

      __builtin_amdgcn_s_setprio(1);
      #pragma unroll
      for (int tk = 0; tk < 2; ++tk) {
        bf16x8 pa = *(const bf16x8*)&Pl[w][l15][tk * 32 + lg * 8];
        #pragma unroll
        for (int c = 0; c < 8; ++c) {
          bf16x8 vb = *(const bf16x8*)&vbr[c * 2 + tk];
          acc[c] = __builtin_amdgcn_mfma_f32_16x16x32_bf16(pa, vb, acc[c], 0, 0, 0);
        }
      }
      __builtin_amdgcn_s_setprio(0);
    }

    // ======== subtile 1
    if (has1) {
      const int kt1 = kt0 + 1;
      {
        const uint4* gv = WV + (size_t)(h * 32 + kt1) * 1024 + l;
        #pragma unroll
        for (int c8 = 0; c8 < 16; ++c8) vbr[c8] = gv[c8 * 64];
      }
      const bool diag = (kt1 == qb);
      const int ctmax = diag ? (w + 1) : 4;
      float p[4][4];
      __builtin_amdgcn_s_setprio(1);
      #pragma unroll
      for (int ct = 0; ct < 4; ++ct) {
        if (ct < ctmax) {
          f32x4 a = (f32x4){0.f, 0.f, 0.f, 0.f};
          #pragma unroll
          for (int t = 0; t < 4; ++t) {
            bf16x8 kb = ((const bf16x8*)Kt[cur])[(16 + ct * 4 + t) * 64 + l];
            a = __builtin_amdgcn_mfma_f32_16x16x32_bf16(kb, qf[t], a, 0, 0, 0);
          }
          #pragma unroll
          for (int r2 = 0; r2 < 4; ++r2) {
            float s = a[r2] * sc2;
            if (diag) {
              const int koff = ct * 16 + lg * 4 + r2;
              s = (koff > w * 16 + l15) ? -1e30f : s;
            }
            p[ct][r2] = s;
          }
        }
      }
      __builtin_amdgcn_s_setprio(0);

      #pragma unroll
      for (int ct = 0; ct < 4; ++ct) {
        if (ct < ctmax) {
          #pragma unroll
          for (int r2 = 0; r2 < 4; ++r2) {
            const float e = exp2f(p[ct][r2]);
            p[ct][r2] = e;
            lrow += e;
          }
        } else {
          #pragma unroll
          for (int r2 = 0; r2 < 4; ++r2) p[ct][r2] = 0.f;
        }
      }

      #pragma unroll
      for (int ct = 0; ct < 4; ++ct) {
        uint2 pk;
        pk.x = (unsigned)f2bf(p[ct][0]) | ((unsigned)f2bf(p[ct][1]) << 16);
        pk.y = (unsigned)f2bf(p[ct][2]) | ((unsigned)f2bf(p[ct][3]) << 16);
        *(uint2*)&Pl[w][l15][ct * 16 + lg * 4] = pk;
      }

      __builtin_amdgcn_s_setprio(1);
      #pragma unroll
      for (int tk = 0; tk < 2; ++tk) {
        bf16x8 pa = *(const bf16x8*)&Pl[w][l15][tk * 32 + lg * 8];
        #pragma unroll
        for (int c = 0; c < 8; ++c) {
          bf16x8 vb = *(const bf16x8*)&vbr[c * 2 + tk];
          acc[c] = __builtin_amdgcn_mfma_f32_16x16x32_bf16(pa, vb, acc[c], 0, 0, 0);
        }
      }
      __builtin_amdgcn_s_setprio(0);
    }

    __syncthreads();   // next pair's K staging drained; all waves done with Kt[cur]
  }

  // deferred row-sum reduction (lanes {l15, l15+16, l15+32, l15+48} share row l15)
  lrow += __shfl_xor(lrow, 16);
  lrow += __shfl_xor(lrow, 32);
  const float inv = 1.0f / lrow;
  float invr[4];
  #pragma unroll
  for (int r2 = 0; r2 < 4; ++r2) invr[r2] = __shfl(inv, lg * 4 + r2);
  #pragma unroll
  for (int r2 = 0; r2 < 4; ++r2) {
    const int row = q0 + w * 16 + lg * 4 + r2;
    float* op = O + O0 + (size_t)(h * SS + row) * DD;
    #pragma unroll
    for (int c = 0; c < 8; ++c)
      op[c * 16 + l15] = acc[c][r2] * invr[r2];
  }
}

// ---------------------------------------------------------------- attention fallback (no ws)
__global__ __launch_bounds__(256) void attn_fb(const float* __restrict__ Q,
                                               const float* __restrict__ K,
                                               const float* __restrict__ V,
                                               float* __restrict__ O) {
  const int h   = blockIdx.x >> 5;
  const int q0  = (blockIdx.x & 31) << 6;
  const int tid = threadIdx.x;
  const int w   = tid >> 6;
  const int l   = tid & 63;
  const int l15 = l & 15;
  const int lg  = l >> 4;

  __shared__ unsigned short Kl[64][136];
  __shared__ unsigned short Vt[128][72];
  __shared__ unsigned short Pl[4][16][72];

  const size_t hbase = (size_t)h * (SS * DD);
  const float* Qh = Q + hbase;
  const float* Kh = K + hbase;
  const float* Vh = V + hbase;

  bf16x8 qf[4];
  {
    const float* qp = Qh + (size_t)(q0 + w * 16 + l15) * DD + lg * 8;
    #pragma unroll
    for (int t = 0; t < 4; ++t) {
      bf16x8 f;
      #pragma unroll
      for (int j = 0; j < 8; ++j) f[j] = (short)f2bf(qp[t * 32 + j]);
      qf[t] = f;
    }
  }

  f32x4 acc[8];
  #pragma unroll
  for (int c = 0; c < 8; ++c) acc[c] = (f32x4){0.f, 0.f, 0.f, 0.f};
  float mrow[4], lrow[4];
  #pragma unroll
  for (int r = 0; r < 4; ++r) { mrow[r] = -1e30f; lrow[r] = 0.f; }

  const float sc2 = 0.08838834764831845f * 1.4426950408889634f;

  const int ntile = (q0 >> 6) + 1;
  for (int kt = 0; kt < ntile; ++kt) {
    const int kv0 = kt << 6;
    __syncthreads();
    for (int idx = tid; idx < 64 * 128; idx += 256) {
      const int kv = idx >> 7, d = idx & 127;
      const size_t g = (size_t)(kv0 + kv) * DD + d;
      Kl[kv][d] = f2bf(Kh[g]);
      Vt[d][kv] = f2bf(Vh[g]);
    }
    __syncthreads();

    f32x4 sacc[4];
    #pragma unroll
    for (int ct = 0; ct < 4; ++ct) {
      f32x4 a = (f32x4){0.f, 0.f, 0.f, 0.f};
      #pragma unroll
      for (int t = 0; t < 4; ++t) {
        bf16x8 kb = *(const bf16x8*)&Kl[ct * 16 + l15][t * 32 + lg * 8];
        a = __builtin_amdgcn_mfma_f32_16x16x32_bf16(qf[t], kb, a, 0, 0, 0);
      }
      sacc[ct] = a;
    }

    float sv[4][4];
    #pragma unroll
    for (int ct = 0; ct < 4; ++ct) {
      const int col = kv0 + ct * 16 + l15;
      #pragma unroll
      for (int r = 0; r < 4; ++r) {
        const int row = q0 + w * 16 + lg * 4 + r;
        sv[ct][r] = (col > row) ? -1e30f : sacc[ct][r] * sc2;
      }
    }

    #pragma unroll
    for (int r = 0; r < 4; ++r) {
      float mt = fmaxf(fmaxf(sv[0][r], sv[1][r]), fmaxf(sv[2][r], sv[3][r]));
      #pragma unroll
      for (int m = 1; m < 16; m <<= 1) mt = fmaxf(mt, __shfl_xor(mt, m));
      const float mn = fmaxf(mrow[r], mt);
      const float al = exp2f(mrow[r] - mn);
      mrow[r] = mn;
      float rs = 0.f;
      #pragma unroll
      for (int ct = 0; ct < 4; ++ct) {
        const float p = exp2f(sv[ct][r] - mn);
        sv[ct][r] = p;
        rs += p;
      }
      #pragma unroll
      for (int m = 1; m < 16; m <<= 1) rs += __shfl_xor(rs, m);
      lrow[r] = lrow[r] * al + rs;
      #pragma unroll
      for (int c = 0; c < 8; ++c) acc[c][r] *= al;
    }

    #pragma unroll
    for (int ct = 0; ct < 4; ++ct)
      #pragma unroll
      for (int r = 0; r < 4; ++r)
        Pl[w][lg * 4 + r][ct * 16 + l15] = f2bf(sv[ct][r]);

    #pragma unroll
    for (int tk = 0; tk < 2; ++tk) {
      bf16x8 pa = *(const bf16x8*)&Pl[w][l15][tk * 32 + lg * 8];
      #pragma unroll
      for (int c = 0; c < 8; ++c) {
        bf16x8 vb = *(const bf16x8*)&Vt[c * 16 + l15][tk * 32 + lg * 8];
        acc[c] = __builtin_amdgcn_mfma_f32_16x16x32_bf16(pa, vb, acc[c], 0, 0, 0);
      }
    }
  }

  #pragma unroll
  for (int r = 0; r < 4; ++r) {
    const float inv = 1.0f / lrow[r];
    const int row = q0 + w * 16 + lg * 4 + r;
    float* op = O + O0 + (size_t)(h * SS + row) * DD;
    #pragma unroll
    for (int c = 0; c < 8; ++c)
      op[c * 16 + l15] = acc[c][r] * inv;
  }
}

// ---------------------------------------------------------------- V path standalone (fallback only)
__global__ __launch_bounds__(256) void v_kernel(const float* __restrict__ V,
                                                float* __restrict__ out) {
  const int gw = (blockIdx.x << 2) + (threadIdx.x >> 6);
  const int l  = threadIdx.x & 63;
  const int s  = gw & (SS - 1);
  const float2 v2 = ((const float2*)(V + (size_t)gw * DD))[l];
  const bool sink = (s < 4);
  const float w0 = sink ? 0.f : v2.x;
  const float w1 = sink ? 0.f : v2.y;
  float a0 = fabsf(w0), a1 = fabsf(w1);
  const int d0 = 2 * l, d1 = 2 * l + 1;

  float oval[4]; int oidx[4]; float scale = 0.f;
  #pragma unroll
  for (int rnd = 0; rnd < 5; ++rnd) {
    float ba; int bd; float bv;
    if (a1 > a0) { ba = a1; bd = d1; bv = w1; }
    else         { ba = a0; bd = d0; bv = w0; }
    #pragma unroll
    for (int m = 1; m < 64; m <<= 1) {
      const float oa = __shfl_xor(ba, m);
      const int   od = __shfl_xor(bd, m);
      const float ov = __shfl_xor(bv, m);
      if (oa > ba || (oa == ba && od < bd)) { ba = oa; bd = od; bv = ov; }
    }
    if (rnd < 4) {
      oval[rnd] = bv; oidx[rnd] = bd;
      if (bd == d0) a0 = -1.f;
      if (bd == d1) a1 = -1.f;
    } else {
      scale = fmaxf(ba, 1e-8f) / 7.0f;
    }
  }

  const bool z0 = (oidx[0] == d0) | (oidx[1] == d0) | (oidx[2] == d0) | (oidx[3] == d0);
  const bool z1 = (oidx[0] == d1) | (oidx[1] == d1) | (oidx[2] == d1) | (oidx[3] == d1);
  const float q0 = z0 ? 0.f : fminf(7.f, fmaxf(-7.f, rintf(w0 / scale)));
  const float q1 = z1 ? 0.f : fminf(7.f, fmaxf(-7.f, rintf(w1 / scale)));
  float2 pack; pack.x = q0; pack.y = q1;
  *(float2*)(out + O5 + (size_t)gw * DD + d0) = pack;

  if (l == 0) {
    out[O6 + gw] = scale;
    #pragma unroll
    for (int j = 0; j < 4; ++j) {
      out[O7 + gw * 4 + j] = oval[j];
      out[O8 + gw * 4 + j] = (float)(gw * DD + oidx[j]);
    }
  }
}

// ---------------------------------------------------------------- fallback K top (no ws)
__global__ __launch_bounds__(256) void k_top(const float* __restrict__ K,
                                             float* __restrict__ out) {
  const int h  = blockIdx.x;
  const int t  = threadIdx.x;
  const int st = t >> 7;
  const float* Kh = K + (size_t)h * (SS * DD);

  __shared__ float lv[256][9];
  __shared__ int   li[256][9];

  float aab[9], av[9]; int ai[9];
  #pragma unroll
  for (int j = 0; j < 9; ++j) { aab[j] = -1.f; av[j] = 0.f; ai[j] = 0; }

  const int d = t & 127;
  const int s0 = st << 10;
  for (int i = 0; i < 1024; ++i) {
    const int s = s0 + i;
    float v = Kh[((size_t)s << 7) + d];
    if (s < 4) v = 0.f;
    const float a = fabsf(v);
    INS9(a, v, s)
  }

  #pragma unroll
  for (int j = 0; j < 9; ++j) { lv[t][j] = av[j]; li[t][j] = ai[j]; }
  __syncthreads();

  if (t < 128) {
    #pragma unroll
    for (int j = 0; j < 9; ++j) {
      const float v = lv[t + 128][j];
      const int  s2 = li[t + 128][j];
      const float a = fabsf(v);
      INS9(a, v, s2)
    }
    const float scale = fmaxf(aab[8], 1e-8f) / 7.0f;
    const unsigned ch = (unsigned)(h * 128 + t);
    out[O2 + ch] = scale;
    #pragma unroll
    for (int j = 0; j < 8; ++j) {
      out[O3 + ch * 8u + j] = av[j];
      out[O4 + ch * 8u + j] = (float)((h * SS + ai[j]) * DD + t);
    }
  }
}

// ---------------------------------------------------------------- sink standalone (fallback only)
__global__ __launch_bounds__(256) void sink_kernel(const float* __restrict__ K,
                                                   const float* __restrict__ V,
                                                   float* __restrict__ out) {
  const int i = blockIdx.x * 256 + threadIdx.x;
  const int h = i >> 9;
  const int r = i & 511;
  const int flat = h * (SS * DD) + r;
  const float fidx = (float)flat;
  out[O3 + 16384u + i]  = K[flat];
  out[O4 + 16384u + i]  = fidx;
  out[O7 + 131072u + i] = V[flat];
  out[O8 + 131072u + i] = fidx;
}

// ---------------------------------------------------------------- K quantize
__global__ __launch_bounds__(256) void k_quant(const float* __restrict__ K,
                                               const float* __restrict__ outr,
                                               float* __restrict__ out) {
  __shared__ float ssc[128];
  __shared__ int   sid[128][8];
  const int e0 = blockIdx.x * 1024;
  const int h  = e0 >> 18;
  if (threadIdx.x < 128) {
    const unsigned ch = (unsigned)(h * 128 + threadIdx.x);
    ssc[threadIdx.x] = outr[O2 + ch];
    #pragma unroll
    for (int j = 0; j < 8; ++j)
      sid[threadIdx.x][j] = ((int)outr[O4 + ch * 8u + j] >> 7) & (SS - 1);
  }
  __syncthreads();

  const int e  = e0 + threadIdx.x * 4;
  const int dd = e & 127;
  const int s  = (e >> 7) & (SS - 1);
  const float4 kv = *(const float4*)(K + e);
  const float vv[4] = {kv.x, kv.y, kv.z, kv.w};
  float4 res;
  float rr[4];
  #pragma unroll
  for (int jj = 0; jj < 4; ++jj) {
    const int d = dd + jj;
    bool zero = (s < 4);
    #pragma unroll
    for (int j = 0; j < 8; ++j) zero |= (sid[d][j] == s);
    rr[jj] = zero ? 0.f : fminf(7.f, fmaxf(-7.f, rintf(vv[jj] / ssc[d])));
  }
  res.x = rr[0]; res.y = rr[1]; res.z = rr[2]; res.w = rr[3];
  *(float4*)(out + O1 + e) = res;
}

extern "C" void kernel_launch(void* const* d_in, const int* in_sizes, int n_in,
                              void* d_out, int out_size, void* d_ws, size_t ws_size,
                              hipStream_t stream) {
  const float* q = (const float*)d_in[0];
  const float* k = (const float*)d_in[1];
  const float* v = (const float*)d_in[2];
  float* out = (float*)d_out;

  const size_t nBF   = 524288;                 // uint4 per K (and per V) bf16 region
  const size_t nPart = (size_t)2048 * 16 * 9;
  const size_t needFull = nBF * 2 * sizeof(uint4) + nPart * 8;  // 19,136,512 B (proven)

  uint4* wsk = (uint4*)d_ws;
  uint4* wsv = wsk + nBF;
  float* wval = (float*)(wsv + nBF);
  int*   widx = (int*)(wval + nPart);

  if (ws_size >= needFull) {
    prep_kv<<<dim3(1792 + HH * SS / 4), dim3(256), 0, stream>>>(k, v, wsk, wsv, wval, widx, out);
    attn_ws<<<dim3(520), dim3(256), 0, stream>>>(q, wsk, wsv, wval, widx, k, v, out);
    k_quant<<<dim3(4096), dim3(256), 0, stream>>>(k, out, out);
  } else {
    attn_fb<<<dim3(512), dim3(256), 0, stream>>>(q, k, v, out);
    v_kernel<<<dim3(HH * SS / 4), dim3(256), 0, stream>>>(v, out);
    k_top<<<dim3(HH), dim3(256), 0, stream>>>(k, out);
    sink_kernel<<<dim3(32), dim3(256), 0, stream>>>(k, v, out);
    k_quant<<<dim3(4096), dim3(256), 0, stream>>>(k, out, out);
  }
}

// Round 19
// 166.042 us; speedup vs baseline: 1.1942x; 1.1942x over previous
//
#include <hip/hip_runtime.h>

#define HH 16
#define SS 2048
#define DD 128

// output offsets (f32 elements) in d_out
#define O0 0u          // attn_output  [1,16,2048,128]
#define O1 4194304u    // k_quant      [1,16,2048,128]
#define O2 8388608u    // k_scale      [1,16,1,128]
#define O3 8390656u    // k_sp_val     [24576]
#define O4 8415232u    // k_sp_idx     [24576]
#define O5 8439808u    // v_quant      [1,16,2048,128]
#define O6 12634112u   // v_scale      [1,16,2048,1]
#define O7 12666880u   // v_sp_val     [139264]
#define O8 12806144u   // v_sp_idx     [139264]

using bf16x8 = __attribute__((ext_vector_type(8))) short;
using f32x4  = __attribute__((ext_vector_type(4))) float;

static __device__ __forceinline__ unsigned short f2bf(float f) {
  union { float f; unsigned u; } x; x.f = f;
  unsigned r = x.u + 0x7fffu + ((x.u >> 16) & 1u);   // RNE
  return (unsigned short)(r >> 16);
}

typedef __attribute__((address_space(1))) const unsigned int gu32_t;
typedef __attribute__((address_space(3))) unsigned int lu32_t;
static __device__ __forceinline__ void gl_lds16(const void* g, void* l) {
  __builtin_amdgcn_global_load_lds((gu32_t*)g, (lu32_t*)l, 16, 0, 0);
}

#define INS9(a_, v_, i_)                                              \
  if ((a_) > aab[8]) {                                                \
    aab[8] = (a_); av[8] = (v_); ai[8] = (i_);                        \
    _Pragma("unroll")                                                 \
    for (int jj = 8; jj > 0; --jj) {                                  \
      if (aab[jj] > aab[jj - 1]) {                                    \
        float ta = aab[jj]; aab[jj] = aab[jj - 1]; aab[jj - 1] = ta;  \
        float tv = av[jj];  av[jj]  = av[jj - 1];  av[jj - 1]  = tv;  \
        int   ti = ai[jj];  ai[jj]  = ai[jj - 1];  ai[jj - 1]  = ti;  \
      }                                                               \
    }                                                                 \
  }

// ---------------------------------------------------------------- prep (flat 1024 blocks):
//  x < 256  : K fragments (2 tiles, pure streaming, no LDS)
//  x < 768  : V transposed fragments — transpose-at-write bf16 staging + b128 chunk reads
//  x < 1024 : K partial top-9 scan (LDS merge only)
__global__ __launch_bounds__(256) void prep_kv(const float* __restrict__ K,
                                               const float* __restrict__ V,
                                               uint4* __restrict__ WK,
                                               uint4* __restrict__ WV,
                                               float* __restrict__ wval,
                                               int* __restrict__ widx) {
  __shared__ unsigned short T2u[128 * 72];   // 18 KB; K-scan aliases scratch onto it
  const int bid = blockIdx.x;
  const int tid = threadIdx.x;

  if (bid < 256) {
    // ---- K fragments for kvt = 2sb, 2sb+1 (pure streaming)
    const int h  = bid >> 4;
    const int sb = bid & 15;
    const float* Kh = K + (size_t)h * (SS * DD);
    for (int slot = tid; slot < 2048; slot += 256) {
      const int tl = slot >> 10, sl = slot & 1023;
      const int chunk = sl >> 6, l = sl & 63;
      const int ct = chunk >> 2, t = chunk & 3;
      const int row = (sb * 2 + tl) * 64 + ct * 16 + (l & 15);
      const float* src = Kh + (size_t)row * DD + t * 32 + (l >> 4) * 8;
      const float4 a = *(const float4*)src;
      const float4 b = *(const float4*)(src + 4);
      uint4 r;
      r.x = (unsigned)f2bf(a.x) | ((unsigned)f2bf(a.y) << 16);
      r.y = (unsigned)f2bf(a.z) | ((unsigned)f2bf(a.w) << 16);
      r.z = (unsigned)f2bf(b.x) | ((unsigned)f2bf(b.y) << 16);
      r.w = (unsigned)f2bf(b.z) | ((unsigned)f2bf(b.w) << 16);
      WK[(size_t)(h * 32 + sb * 2 + tl) * 1024 + sl] = r;
    }

  } else if (bid < 768) {
    // ---- V path: transpose at write time. T2u[n][k^swz(n)] = bf16(V[k][n]), stride 72 (144B = 16*9)
    const int ht = bid - 256;
    const float* Vh = V + (size_t)(ht >> 5) * (SS * DD) + (size_t)(ht & 31) * 64 * DD;

    #pragma unroll
    for (int it = 0; it < 4; ++it) {
      const int p   = it * 256 + tid;      // 1024 row-pairs
      const int row = (p >> 5) * 2;        // even row
      const int col = (p & 31) * 4;
      const float4 a = *(const float4*)(Vh + (size_t)row * DD + col);
      const float4 b = *(const float4*)(Vh + (size_t)(row + 1) * DD + col);
      const float avv[4] = {a.x, a.y, a.z, a.w};
      const float bvv[4] = {b.x, b.y, b.z, b.w};
      #pragma unroll
      for (int jj = 0; jj < 4; ++jj) {
        const int n   = col + jj;
        const int swz = ((n >> 3) & 7) << 3;
        const int kk  = row ^ swz;         // even; kk+1 == (row+1)^swz
        unsigned pk = (unsigned)f2bf(avv[jj]) | ((unsigned)f2bf(bvv[jj]) << 16);
        *(unsigned*)&T2u[n * 72 + kk] = pk;
      }
    }
    __syncthreads();

    // WV chunks: chunk=c*2+tk ; lane l = V[tk*32+(l>>4)*8+j][c*16+(l&15)], j=0..7 — one b128 each
    uint4* dst = WV + (size_t)ht * 1024;
    #pragma unroll
    for (int it = 0; it < 4; ++it) {
      const int slot = it * 256 + tid;
      const int chunk = slot >> 6, l = slot & 63;
      const int c = chunk >> 1, tk = chunk & 1;
      const int n   = c * 16 + (l & 15);
      const int k0  = tk * 32 + (l >> 4) * 8;
      const int swz = ((n >> 3) & 7) << 3;
      dst[slot] = *(const uint4*)&T2u[n * 72 + (k0 ^ swz)];
    }

  } else {
    // ---- K scan: partial top-9 over 128-token stripe (h, sb)
    const int xb = bid - 768;
    const int h  = xb >> 4;
    const int sb = xb & 15;
    const float* Kh = K + (size_t)h * (SS * DD);
    const int d   = tid & 127;
    const int sub = tid >> 7;
    const int s0  = sb * 128 + sub * 64;

    float aab[9], av[9]; int ai[9];
    #pragma unroll
    for (int j = 0; j < 9; ++j) { aab[j] = -1.f; av[j] = 0.f; ai[j] = 0; }
    for (int ib = 0; ib < 64; ib += 8) {
      float vv[8];
      #pragma unroll
      for (int u = 0; u < 8; ++u)
        vv[u] = Kh[((size_t)(s0 + ib + u) << 7) + d];
      #pragma unroll
      for (int u = 0; u < 8; ++u) {
        const int s = s0 + ib + u;
        const float v = (s < 4) ? 0.f : vv[u];          // sink zeroing (k_iso)
        const float a = fabsf(v);
        INS9(a, v, s)
      }
    }
    float* lvf = (float*)T2u;               // alias scratch (needs 9216 B, have 18432)
    int*   lii = (int*)T2u + 1152;
    if (sub == 1) {
      #pragma unroll
      for (int j = 0; j < 9; ++j) { lvf[d * 9 + j] = av[j]; lii[d * 9 + j] = ai[j]; }
    }
    __syncthreads();
    if (sub == 0) {
      #pragma unroll
      for (int j = 0; j < 9; ++j) {                     // merge sub1 (higher tokens)
        const float v = lvf[d * 9 + j];
        const int  s2 = lii[d * 9 + j];
        const float a = fabsf(v);
        INS9(a, v, s2)
      }
      const int base = (sb * 2048 + h * 128 + d) * 9;   // [sb][2048 ch][9] coalesced
      #pragma unroll
      for (int j = 0; j < 9; ++j) { wval[base + j] = av[j]; widx[base + j] = ai[j]; }
    }
  }
}

// ---------------------------------------------------------------- attention dispatch:
//  bid < 8   : K merge + sink appends (FIRST — overlaps attn instead of tailing it)
//  bid >= 8  : attention — 128-k per barrier (2 subtiles), deferred row-sum reduce
__global__ __launch_bounds__(256) void attn_ws(const float* __restrict__ Q,
                                               const uint4* __restrict__ WK,
                                               const uint4* __restrict__ WV,
                                               const float* __restrict__ wval,
                                               const int* __restrict__ widx,
                                               const float* __restrict__ K,
                                               const float* __restrict__ V,
                                               float* __restrict__ O) {
  const int bid = blockIdx.x;
  const int tid = threadIdx.x;

  if (bid < 8) {
    // ---- K merge: coalesced partials + reg double-buffer (8 blocks x 256)
    const int ch = bid * 256 + tid;                // 2048 channels
    const int h = ch >> 7, d = ch & 127;

    float aab[9], av[9]; int ai[9];
    #pragma unroll
    for (int j = 0; j < 9; ++j) { aab[j] = -1.f; av[j] = 0.f; ai[j] = 0; }

    float va[9], vb[9]; int ia[9], ib[9];
    {
      const int b0 = ch * 9;                       // sb = 0
      #pragma unroll
      for (int j = 0; j < 9; ++j) { va[j] = wval[b0 + j]; ia[j] = widx[b0 + j]; }
    }
    for (int sb = 0; sb < 16; ++sb) {              // token order -> stable ties
      if (sb < 15) {
        const int nb = ((sb + 1) * 2048 + ch) * 9; // prefetch next stripe
        #pragma unroll
        for (int j = 0; j < 9; ++j) { vb[j] = wval[nb + j]; ib[j] = widx[nb + j]; }
      }
      #pragma unroll
      for (int j = 0; j < 9; ++j) {
        const float v = va[j];
        const int  si = ia[j];
        const float a = fabsf(v);
        INS9(a, v, si)
      }
      #pragma unroll
      for (int j = 0; j < 9; ++j) { va[j] = vb[j]; ia[j] = ib[j]; }
    }

    const float scale = fmaxf(aab[8], 1e-8f) / 7.0f;
    O[O2 + ch] = scale;
    #pragma unroll
    for (int j = 0; j < 8; ++j) {
      O[O3 + ch * 8u + j] = av[j];
      O[O4 + ch * 8u + j] = (float)((h * SS + ai[j]) * DD + d);
    }
    #pragma unroll
    for (int u = 0; u < 4; ++u) {
      const int i  = ch * 4 + u;
      const int hh = i >> 9;
      const int r  = i & 511;
      const int flat = hh * (SS * DD) + r;
      const float fidx = (float)flat;
      O[O3 + 16384u + i]  = K[flat];
      O[O4 + 16384u + i]  = fidx;
      O[O7 + 131072u + i] = V[flat];
      O[O8 + 131072u + i] = fidx;
    }
    return;
  }

  const int abid = bid - 8;
  const int x  = abid & 7;          // XCD
  const int kk = abid >> 3;
  const int p_ = kk >> 5;
  const int r  = kk & 31;
  const int h  = x * 2 + (r & 1);
  const int jj = r >> 1;
  const int qb = p_ ? (31 - jj) : jj;  // CU-pair balance: qb with 31-qb
  const int q0 = qb << 6;
  const int w   = tid >> 6;
  const int l   = tid & 63;
  const int l15 = l & 15;
  const int lg  = l >> 4;

  __shared__ uint4 Kt[2][2048];            // 2 x 32 KB (pair of 64-k subtiles per buffer)
  __shared__ unsigned short Pl[4][16][72]; // per-wave P buffer (row = q-local)

  bf16x8 qf[4];
  {
    const float* qp = Q + (size_t)h * (SS * DD) + (size_t)(q0 + w * 16 + l15) * DD + lg * 8;
    #pragma unroll
    for (int t = 0; t < 4; ++t) {
      const float4 a = *(const float4*)(qp + t * 32);
      const float4 b = *(const float4*)(qp + t * 32 + 4);
      bf16x8 f;
      f[0] = (short)f2bf(a.x); f[1] = (short)f2bf(a.y);
      f[2] = (short)f2bf(a.z); f[3] = (short)f2bf(a.w);
      f[4] = (short)f2bf(b.x); f[5] = (short)f2bf(b.y);
      f[6] = (short)f2bf(b.z); f[7] = (short)f2bf(b.w);
      qf[t] = f;
    }
  }

  f32x4 acc[8];
  #pragma unroll
  for (int c = 0; c < 8; ++c) acc[c] = (f32x4){0.f, 0.f, 0.f, 0.f};
  float lrow = 0.f;                  // per-lane partial denom; reduced ONCE in epilogue

  const float sc2 = 0.08838834764831845f * 1.4426950408889634f;  // /sqrt(128)*log2(e)

  // prologue: stage tiles 0,1 into buffer 0 — 8 chunks per wave
  {
    const size_t tbase = (size_t)(h * 32) * 1024;
    #pragma unroll
    for (int i = 0; i < 8; ++i) {
      const int ch = (w << 3) + i;             // 0..31
      gl_lds16(WK + tbase + ch * 64 + l, &Kt[0][ch * 64]);
    }
  }
  __syncthreads();

  const int npair = (qb >> 1) + 1;
  for (int it = 0; it < npair; ++it) {
    const int cur = it & 1;
    const int kt0 = it * 2;
    const bool has1 = (kt0 + 1 <= qb);

    // V frags for kt0 -> regs (coalesced; latency hides under QK0)
    uint4 vbr[16];
    {
      const uint4* gv = WV + (size_t)(h * 32 + kt0) * 1024 + l;
      #pragma unroll
      for (int c8 = 0; c8 < 16; ++c8) vbr[c8] = gv[c8 * 64];
    }

    // issue next pair's K staging
    if (it + 1 < npair) {
      const size_t tbase = (size_t)(h * 32 + kt0 + 2) * 1024;
      #pragma unroll
      for (int i = 0; i < 8; ++i) {
        const int ch = (w << 3) + i;
        gl_lds16(WK + tbase + ch * 64 + l, &Kt[cur ^ 1][ch * 64]);
      }
    }

    // ======== subtile 0
    {
      const bool diag = (kt0 == qb);
      const int ctmax = diag ? (w + 1) : 4;
      float p[4][4];
      __builtin_amdgcn_s_setprio(1);
      #pragma unroll
      for (int ct = 0; ct < 4; ++ct) {
        if (ct < ctmax) {
          f32x4 a = (f32x4){0.f, 0.f, 0.f, 0.f};
          #pragma unroll
          for (int t = 0; t < 4; ++t) {
            bf16x8 kb = ((const bf16x8*)Kt[cur])[(ct * 4 + t) * 64 + l];
            a = __builtin_amdgcn_mfma_f32_16x16x32_bf16(kb, qf[t], a, 0, 0, 0);
          }
          #pragma unroll
          for (int r2 = 0; r2 < 4; ++r2) {
            float s = a[r2] * sc2;
            if (diag) {
              const int koff = ct * 16 + lg * 4 + r2;
              s = (koff > w * 16 + l15) ? -1e30f : s;
            }
            p[ct][r2] = s;
          }
        }
      }
      __builtin_amdgcn_s_setprio(0);

      #pragma unroll
      for (int ct = 0; ct < 4; ++ct) {
        if (ct < ctmax) {
          #pragma unroll
          for (int r2 = 0; r2 < 4; ++r2) {
            const float e = exp2f(p[ct][r2]);
            p[ct][r2] = e;
            lrow += e;
          }
        } else {
          #pragma unroll
          for (int r2 = 0; r2 < 4; ++r2) p[ct][r2] = 0.f;
        }
      }

      #pragma unroll
      for (int ct = 0; ct < 4; ++ct) {
        uint2 pk;
        pk.x = (unsigned)f2bf(p[ct][0]) | ((unsigned)f2bf(p[ct][1]) << 16);
        pk.y = (unsigned)f2bf(p[ct][2]) | ((unsigned)f2bf(p[ct][3]) << 16);
        *(uint2*)&Pl[w][l15][ct * 16 + lg * 4] = pk;
      }

      __builtin_amdgcn_s_setprio(1);
      #pragma unroll
      for (int tk = 0; tk < 2; ++tk) {
        bf16x8 pa = *(const bf16x8*)&Pl[w][l15][tk * 32 + lg * 8];
        #pragma unroll
        for (int c = 0; c < 8; ++c) {
          bf16x8 vb = *(const bf16x8*)&vbr[c * 2 + tk];
          acc[c] = __builtin_amdgcn_mfma_f32_16x16x32_bf16(pa, vb, acc[c], 0, 0, 0);
        }
      }
      __builtin_amdgcn_s_setprio(0);
    }

    // ======== subtile 1
    if (has1) {
      const int kt1 = kt0 + 1;
      {
        const uint4* gv = WV + (size_t)(h * 32 + kt1) * 1024 + l;
        #pragma unroll
        for (int c8 = 0; c8 < 16; ++c8) vbr[c8] = gv[c8 * 64];
      }
      const bool diag = (kt1 == qb);
      const int ctmax = diag ? (w + 1) : 4;
      float p[4][4];
      __builtin_amdgcn_s_setprio(1);
      #pragma unroll
      for (int ct = 0; ct < 4; ++ct) {
        if (ct < ctmax) {
          f32x4 a = (f32x4){0.f, 0.f, 0.f, 0.f};
          #pragma unroll
          for (int t = 0; t < 4; ++t) {
            bf16x8 kb = ((const bf16x8*)Kt[cur])[(16 + ct * 4 + t) * 64 + l];
            a = __builtin_amdgcn_mfma_f32_16x16x32_bf16(kb, qf[t], a, 0, 0, 0);
          }
          #pragma unroll
          for (int r2 = 0; r2 < 4; ++r2) {
            float s = a[r2] * sc2;
            if (diag) {
              const int koff = ct * 16 + lg * 4 + r2;
              s = (koff > w * 16 + l15) ? -1e30f : s;
            }
            p[ct][r2] = s;
          }
        }
      }
      __builtin_amdgcn_s_setprio(0);

      #pragma unroll
      for (int ct = 0; ct < 4; ++ct) {
        if (ct < ctmax) {
          #pragma unroll
          for (int r2 = 0; r2 < 4; ++r2) {
            const float e = exp2f(p[ct][r2]);
            p[ct][r2] = e;
            lrow += e;
          }
        } else {
          #pragma unroll
          for (int r2 = 0; r2 < 4; ++r2) p[ct][r2] = 0.f;
        }
      }

      #pragma unroll
      for (int ct = 0; ct < 4; ++ct) {
        uint2 pk;
        pk.x = (unsigned)f2bf(p[ct][0]) | ((unsigned)f2bf(p[ct][1]) << 16);
        pk.y = (unsigned)f2bf(p[ct][2]) | ((unsigned)f2bf(p[ct][3]) << 16);
        *(uint2*)&Pl[w][l15][ct * 16 + lg * 4] = pk;
      }

      __builtin_amdgcn_s_setprio(1);
      #pragma unroll
      for (int tk = 0; tk < 2; ++tk) {
        bf16x8 pa = *(const bf16x8*)&Pl[w][l15][tk * 32 + lg * 8];
        #pragma unroll
        for (int c = 0; c < 8; ++c) {
          bf16x8 vb = *(const bf16x8*)&vbr[c * 2 + tk];
          acc[c] = __builtin_amdgcn_mfma_f32_16x16x32_bf16(pa, vb, acc[c], 0, 0, 0);
        }
      }
      __builtin_amdgcn_s_setprio(0);
    }

    __syncthreads();   // next pair's K staging drained; all waves done with Kt[cur]
  }

  // deferred row-sum reduction (lanes {l15, l15+16, l15+32, l15+48} share row l15)
  lrow += __shfl_xor(lrow, 16);
  lrow += __shfl_xor(lrow, 32);
  const float inv = 1.0f / lrow;
  float invr[4];
  #pragma unroll
  for (int r2 = 0; r2 < 4; ++r2) invr[r2] = __shfl(inv, lg * 4 + r2);
  #pragma unroll
  for (int r2 = 0; r2 < 4; ++r2) {
    const int row = q0 + w * 16 + lg * 4 + r2;
    float* op = O + O0 + (size_t)(h * SS + row) * DD;
    #pragma unroll
    for (int c = 0; c < 8; ++c)
      op[c * 16 + l15] = acc[c][r2] * invr[r2];
  }
}

// ---------------------------------------------------------------- attention fallback (no ws)
__global__ __launch_bounds__(256) void attn_fb(const float* __restrict__ Q,
                                               const float* __restrict__ K,
                                               const float* __restrict__ V,
                                               float* __restrict__ O) {
  const int h   = blockIdx.x >> 5;
  const int q0  = (blockIdx.x & 31) << 6;
  const int tid = threadIdx.x;
  const int w   = tid >> 6;
  const int l   = tid & 63;
  const int l15 = l & 15;
  const int lg  = l >> 4;

  __shared__ unsigned short Kl[64][136];
  __shared__ unsigned short Vt[128][72];
  __shared__ unsigned short Pl[4][16][72];

  const size_t hbase = (size_t)h * (SS * DD);
  const float* Qh = Q + hbase;
  const float* Kh = K + hbase;
  const float* Vh = V + hbase;

  bf16x8 qf[4];
  {
    const float* qp = Qh + (size_t)(q0 + w * 16 + l15) * DD + lg * 8;
    #pragma unroll
    for (int t = 0; t < 4; ++t) {
      bf16x8 f;
      #pragma unroll
      for (int j = 0; j < 8; ++j) f[j] = (short)f2bf(qp[t * 32 + j]);
      qf[t] = f;
    }
  }

  f32x4 acc[8];
  #pragma unroll
  for (int c = 0; c < 8; ++c) acc[c] = (f32x4){0.f, 0.f, 0.f, 0.f};
  float mrow[4], lrow[4];
  #pragma unroll
  for (int r = 0; r < 4; ++r) { mrow[r] = -1e30f; lrow[r] = 0.f; }

  const float sc2 = 0.08838834764831845f * 1.4426950408889634f;

  const int ntile = (q0 >> 6) + 1;
  for (int kt = 0; kt < ntile; ++kt) {
    const int kv0 = kt << 6;
    __syncthreads();
    for (int idx = tid; idx < 64 * 128; idx += 256) {
      const int kv = idx >> 7, d = idx & 127;
      const size_t g = (size_t)(kv0 + kv) * DD + d;
      Kl[kv][d] = f2bf(Kh[g]);
      Vt[d][kv] = f2bf(Vh[g]);
    }
    __syncthreads();

    f32x4 sacc[4];
    #pragma unroll
    for (int ct = 0; ct < 4; ++ct) {
      f32x4 a = (f32x4){0.f, 0.f, 0.f, 0.f};
      #pragma unroll
      for (int t = 0; t < 4; ++t) {
        bf16x8 kb = *(const bf16x8*)&Kl[ct * 16 + l15][t * 32 + lg * 8];
        a = __builtin_amdgcn_mfma_f32_16x16x32_bf16(qf[t], kb, a, 0, 0, 0);
      }
      sacc[ct] = a;
    }

    float sv[4][4];
    #pragma unroll
    for (int ct = 0; ct < 4; ++ct) {
      const int col = kv0 + ct * 16 + l15;
      #pragma unroll
      for (int r = 0; r < 4; ++r) {
        const int row = q0 + w * 16 + lg * 4 + r;
        sv[ct][r] = (col > row) ? -1e30f : sacc[ct][r] * sc2;
      }
    }

    #pragma unroll
    for (int r = 0; r < 4; ++r) {
      float mt = fmaxf(fmaxf(sv[0][r], sv[1][r]), fmaxf(sv[2][r], sv[3][r]));
      #pragma unroll
      for (int m = 1; m < 16; m <<= 1) mt = fmaxf(mt, __shfl_xor(mt, m));
      const float mn = fmaxf(mrow[r], mt);
      const float al = exp2f(mrow[r] - mn);
      mrow[r] = mn;
      float rs = 0.f;
      #pragma unroll
      for (int ct = 0; ct < 4; ++ct) {
        const float p = exp2f(sv[ct][r] - mn);
        sv[ct][r] = p;
        rs += p;
      }
      #pragma unroll
      for (int m = 1; m < 16; m <<= 1) rs += __shfl_xor(rs, m);
      lrow[r] = lrow[r] * al + rs;
      #pragma unroll
      for (int c = 0; c < 8; ++c) acc[c][r] *= al;
    }

    #pragma unroll
    for (int ct = 0; ct < 4; ++ct)
      #pragma unroll
      for (int r = 0; r < 4; ++r)
        Pl[w][lg * 4 + r][ct * 16 + l15] = f2bf(sv[ct][r]);

    #pragma unroll
    for (int tk = 0; tk < 2; ++tk) {
      bf16x8 pa = *(const bf16x8*)&Pl[w][l15][tk * 32 + lg * 8];
      #pragma unroll
      for (int c = 0; c < 8; ++c) {
        bf16x8 vb = *(const bf16x8*)&Vt[c * 16 + l15][tk * 32 + lg * 8];
        acc[c] = __builtin_amdgcn_mfma_f32_16x16x32_bf16(pa, vb, acc[c], 0, 0, 0);
      }
    }
  }

  #pragma unroll
  for (int r = 0; r < 4; ++r) {
    const float inv = 1.0f / lrow[r];
    const int row = q0 + w * 16 + lg * 4 + r;
    float* op = O + O0 + (size_t)(h * SS + row) * DD;
    #pragma unroll
    for (int c = 0; c < 8; ++c)
      op[c * 16 + l15] = acc[c][r] * inv;
  }
}

// ---------------------------------------------------------------- V path standalone (fallback only)
__global__ __launch_bounds__(256) void v_kernel(const float* __restrict__ V,
                                                float* __restrict__ out) {
  const int gw = (blockIdx.x << 2) + (threadIdx.x >> 6);
  const int l  = threadIdx.x & 63;
  const int s  = gw & (SS - 1);
  const float2 v2 = ((const float2*)(V + (size_t)gw * DD))[l];
  const bool sink = (s < 4);
  const float w0 = sink ? 0.f : v2.x;
  const float w1 = sink ? 0.f : v2.y;
  float a0 = fabsf(w0), a1 = fabsf(w1);
  const int d0 = 2 * l, d1 = 2 * l + 1;

  float oval[4]; int oidx[4]; float scale = 0.f;
  #pragma unroll
  for (int rnd = 0; rnd < 5; ++rnd) {
    float ba; int bd; float bv;
    if (a1 > a0) { ba = a1; bd = d1; bv = w1; }
    else         { ba = a0; bd = d0; bv = w0; }
    #pragma unroll
    for (int m = 1; m < 64; m <<= 1) {
      const float oa = __shfl_xor(ba, m);
      const int   od = __shfl_xor(bd, m);
      const float ov = __shfl_xor(bv, m);
      if (oa > ba || (oa == ba && od < bd)) { ba = oa; bd = od; bv = ov; }
    }
    if (rnd < 4) {
      oval[rnd] = bv; oidx[rnd] = bd;
      if (bd == d0) a0 = -1.f;
      if (bd == d1) a1 = -1.f;
    } else {
      scale = fmaxf(ba, 1e-8f) / 7.0f;
    }
  }

  const bool z0 = (oidx[0] == d0) | (oidx[1] == d0) | (oidx[2] == d0) | (oidx[3] == d0);
  const bool z1 = (oidx[0] == d1) | (oidx[1] == d1) | (oidx[2] == d1) | (oidx[3] == d1);
  const float q0 = z0 ? 0.f : fminf(7.f, fmaxf(-7.f, rintf(w0 / scale)));
  const float q1 = z1 ? 0.f : fminf(7.f, fmaxf(-7.f, rintf(w1 / scale)));
  float2 pack; pack.x = q0; pack.y = q1;
  *(float2*)(out + O5 + (size_t)gw * DD + d0) = pack;

  if (l == 0) {
    out[O6 + gw] = scale;
    #pragma unroll
    for (int j = 0; j < 4; ++j) {
      out[O7 + gw * 4 + j] = oval[j];
      out[O8 + gw * 4 + j] = (float)(gw * DD + oidx[j]);
    }
  }
}

// ---------------------------------------------------------------- fallback K top (no ws)
__global__ __launch_bounds__(256) void k_top(const float* __restrict__ K,
                                             float* __restrict__ out) {
  const int h  = blockIdx.x;
  const int t  = threadIdx.x;
  const int st = t >> 7;
  const float* Kh = K + (size_t)h * (SS * DD);

  __shared__ float lv[256][9];
  __shared__ int   li[256][9];

  float aab[9], av[9]; int ai[9];
  #pragma unroll
  for (int j = 0; j < 9; ++j) { aab[j] = -1.f; av[j] = 0.f; ai[j] = 0; }

  const int d = t & 127;
  const int s0 = st << 10;
  for (int i = 0; i < 1024; ++i) {
    const int s = s0 + i;
    float v = Kh[((size_t)s << 7) + d];
    if (s < 4) v = 0.f;
    const float a = fabsf(v);
    INS9(a, v, s)
  }

  #pragma unroll
  for (int j = 0; j < 9; ++j) { lv[t][j] = av[j]; li[t][j] = ai[j]; }
  __syncthreads();

  if (t < 128) {
    #pragma unroll
    for (int j = 0; j < 9; ++j) {
      const float v = lv[t + 128][j];
      const int  s2 = li[t + 128][j];
      const float a = fabsf(v);
      INS9(a, v, s2)
    }
    const float scale = fmaxf(aab[8], 1e-8f) / 7.0f;
    const unsigned ch = (unsigned)(h * 128 + t);
    out[O2 + ch] = scale;
    #pragma unroll
    for (int j = 0; j < 8; ++j) {
      out[O3 + ch * 8u + j] = av[j];
      out[O4 + ch * 8u + j] = (float)((h * SS + ai[j]) * DD + t);
    }
  }
}

// ---------------------------------------------------------------- sink standalone (fallback only)
__global__ __launch_bounds__(256) void sink_kernel(const float* __restrict__ K,
                                                   const float* __restrict__ V,
                                                   float* __restrict__ out) {
  const int i = blockIdx.x * 256 + threadIdx.x;
  const int h = i >> 9;
  const int r = i & 511;
  const int flat = h * (SS * DD) + r;
  const float fidx = (float)flat;
  out[O3 + 16384u + i]  = K[flat];
  out[O4 + 16384u + i]  = fidx;
  out[O7 + 131072u + i] = V[flat];
  out[O8 + 131072u + i] = fidx;
}

// ---------------------------------------------------------------- K quantize (+ V quant blocks >= 4096)
__global__ __launch_bounds__(256) void k_quant(const float* __restrict__ K,
                                               const float* __restrict__ V,
                                               const float* __restrict__ outr,
                                               float* __restrict__ out) {
  const int bid = blockIdx.x;
  const int tid = threadIdx.x;

  if (bid >= 4096) {
    // ---- V quant: one wave per token, register-only (small-LDS kernel -> full occupancy)
    const int gw = ((bid - 4096) << 2) + (tid >> 6);  // token id h*S+s
    const int l  = tid & 63;
    const int s  = gw & (SS - 1);
    const float2 v2 = ((const float2*)(V + (size_t)gw * DD))[l];
    const bool sink = (s < 4);
    const float w0 = sink ? 0.f : v2.x;
    const float w1 = sink ? 0.f : v2.y;
    float a0 = fabsf(w0), a1 = fabsf(w1);
    const int d0 = 2 * l, d1 = 2 * l + 1;

    float oval[4]; int oidx[4]; float scale = 0.f;
    #pragma unroll
    for (int rnd = 0; rnd < 5; ++rnd) {
      float ba; int bd; float bv;
      if (a1 > a0) { ba = a1; bd = d1; bv = w1; }
      else         { ba = a0; bd = d0; bv = w0; }
      #pragma unroll
      for (int m = 1; m < 64; m <<= 1) {
        const float oa = __shfl_xor(ba, m);
        const int   od = __shfl_xor(bd, m);
        const float ov = __shfl_xor(bv, m);
        if (oa > ba || (oa == ba && od < bd)) { ba = oa; bd = od; bv = ov; }
      }
      if (rnd < 4) {
        oval[rnd] = bv; oidx[rnd] = bd;
        if (bd == d0) a0 = -1.f;
        if (bd == d1) a1 = -1.f;
      } else {
        scale = fmaxf(ba, 1e-8f) / 7.0f;   // 5th largest = absmax of dense remainder
      }
    }

    const bool z0 = (oidx[0] == d0) | (oidx[1] == d0) | (oidx[2] == d0) | (oidx[3] == d0);
    const bool z1 = (oidx[0] == d1) | (oidx[1] == d1) | (oidx[2] == d1) | (oidx[3] == d1);
    const float q0 = z0 ? 0.f : fminf(7.f, fmaxf(-7.f, rintf(w0 / scale)));
    const float q1 = z1 ? 0.f : fminf(7.f, fmaxf(-7.f, rintf(w1 / scale)));
    float2 pack; pack.x = q0; pack.y = q1;
    *(float2*)(out + O5 + (size_t)gw * DD + d0) = pack;

    if (l == 0) {
      out[O6 + gw] = scale;
      #pragma unroll
      for (int j = 0; j < 4; ++j) {
        out[O7 + gw * 4 + j] = oval[j];
        out[O8 + gw * 4 + j] = (float)(gw * DD + oidx[j]);   // exact (< 2^23)
      }
    }
    return;
  }

  __shared__ float ssc[128];
  __shared__ int   sid[128][8];
  const int e0 = bid * 1024;
  const int h  = e0 >> 18;
  if (tid < 128) {
    const unsigned ch = (unsigned)(h * 128 + tid);
    ssc[tid] = outr[O2 + ch];
    #pragma unroll
    for (int j = 0; j < 8; ++j)
      sid[tid][j] = ((int)outr[O4 + ch * 8u + j] >> 7) & (SS - 1);
  }
  __syncthreads();

  const int e  = e0 + tid * 4;
  const int dd = e & 127;
  const int s  = (e >> 7) & (SS - 1);
  const float4 kv = *(const float4*)(K + e);
  const float vv[4] = {kv.x, kv.y, kv.z, kv.w};
  float4 res;
  float rr[4];
  #pragma unroll
  for (int jj = 0; jj < 4; ++jj) {
    const int d = dd + jj;
    bool zero = (s < 4);
    #pragma unroll
    for (int j = 0; j < 8; ++j) zero |= (sid[d][j] == s);
    rr[jj] = zero ? 0.f : fminf(7.f, fmaxf(-7.f, rintf(vv[jj] / ssc[d])));
  }
  res.x = rr[0]; res.y = rr[1]; res.z = rr[2]; res.w = rr[3];
  *(float4*)(out + O1 + e) = res;
}

extern "C" void kernel_launch(void* const* d_in, const int* in_sizes, int n_in,
                              void* d_out, int out_size, void* d_ws, size_t ws_size,
                              hipStream_t stream) {
  const float* q = (const float*)d_in[0];
  const float* k = (const float*)d_in[1];
  const float* v = (const float*)d_in[2];
  float* out = (float*)d_out;

  const size_t nBF   = 524288;                 // uint4 per K (and per V) bf16 region
  const size_t nPart = (size_t)2048 * 16 * 9;
  const size_t needFull = nBF * 2 * sizeof(uint4) + nPart * 8;  // 19,136,512 B (proven)

  uint4* wsk = (uint4*)d_ws;
  uint4* wsv = wsk + nBF;
  float* wval = (float*)(wsv + nBF);
  int*   widx = (int*)(wval + nPart);

  if (ws_size >= needFull) {
    prep_kv<<<dim3(1024), dim3(256), 0, stream>>>(k, v, wsk, wsv, wval, widx);
    attn_ws<<<dim3(520), dim3(256), 0, stream>>>(q, wsk, wsv, wval, widx, k, v, out);
    k_quant<<<dim3(4096 + HH * SS / 4), dim3(256), 0, stream>>>(k, v, out, out);
  } else {
    attn_fb<<<dim3(512), dim3(256), 0, stream>>>(q, k, v, out);
    v_kernel<<<dim3(HH * SS / 4), dim3(256), 0, stream>>>(v, out);
    k_top<<<dim3(HH), dim3(256), 0, stream>>>(k, out);
    sink_kernel<<<dim3(32), dim3(256), 0, stream>>>(k, v, out);
    k_quant<<<dim3(4096), dim3(256), 0, stream>>>(k, v, out, out);
  }
}